// Round 1
// baseline (40.683 us; speedup 1.0000x reference)
//
#include <hip/hip_runtime.h>

#define NB 32
#define TT 4096
#define DD 768
#define NJ 64
#define NK 64

// One block per (doc, clause). 4 waves; each wave processes rows k, k+4, ...
// Row dot-products vs fc_w and emo_w -> LDS; wave 0 does softmax + sigmoid.
__global__ __launch_bounds__(256) void clause_pool_kernel(
    const float* __restrict__ hs,         // [B, T, D]
    const int*   __restrict__ clause_len, // [B, J]
    const float* __restrict__ fc_w,       // [D]
    const float* __restrict__ fc_b,       // [1]
    const float* __restrict__ emo_w,      // [D]
    const float* __restrict__ emo_b,      // [1]
    float*       __restrict__ out)        // [B, J]
{
    const int bj   = blockIdx.x;
    const int b    = bj >> 6;
    const int j    = bj & 63;
    const int tid  = threadIdx.x;
    const int lane = tid & 63;
    const int wave = tid >> 6;

    // Weight fragments: lane owns float4 chunks {lane, lane+64, lane+128} (192 total = 768 floats)
    const float4* fw4 = (const float4*)fc_w;
    const float4* ew4 = (const float4*)emo_w;
    const float4 wf0 = fw4[lane], wf1 = fw4[lane + 64], wf2 = fw4[lane + 128];
    const float4 we0 = ew4[lane], we1 = ew4[lane + 64], we2 = ew4[lane + 128];

    // Clause start = exclusive prefix sum of clause_len[b, :j]; clen = clause_len[b, j].
    // Each wave computes it redundantly (cheap, L2-resident).
    const int cl   = clause_len[(b << 6) + lane];
    const int clen = __shfl(cl, j, 64);
    int pre = (lane < j) ? cl : 0;
    #pragma unroll
    for (int s = 1; s < 64; s <<= 1) pre += __shfl_xor(pre, s, 64);
    const int start = pre;

    __shared__ float sfc[NK];
    __shared__ float sem[NK];

    const float* base = hs + ((size_t)b * TT + (size_t)start) * DD;

    for (int k = wave; k < clen; k += 4) {
        const float4* row = (const float4*)(base + (size_t)k * DD);
        const float4 h0 = row[lane];
        const float4 h1 = row[lane + 64];
        const float4 h2 = row[lane + 128];

        float pf = h0.x * wf0.x;
        pf = fmaf(h0.y, wf0.y, pf); pf = fmaf(h0.z, wf0.z, pf); pf = fmaf(h0.w, wf0.w, pf);
        pf = fmaf(h1.x, wf1.x, pf); pf = fmaf(h1.y, wf1.y, pf);
        pf = fmaf(h1.z, wf1.z, pf); pf = fmaf(h1.w, wf1.w, pf);
        pf = fmaf(h2.x, wf2.x, pf); pf = fmaf(h2.y, wf2.y, pf);
        pf = fmaf(h2.z, wf2.z, pf); pf = fmaf(h2.w, wf2.w, pf);

        float pe = h0.x * we0.x;
        pe = fmaf(h0.y, we0.y, pe); pe = fmaf(h0.z, we0.z, pe); pe = fmaf(h0.w, we0.w, pe);
        pe = fmaf(h1.x, we1.x, pe); pe = fmaf(h1.y, we1.y, pe);
        pe = fmaf(h1.z, we1.z, pe); pe = fmaf(h1.w, we1.w, pe);
        pe = fmaf(h2.x, we2.x, pe); pe = fmaf(h2.y, we2.y, pe);
        pe = fmaf(h2.z, we2.z, pe); pe = fmaf(h2.w, we2.w, pe);

        #pragma unroll
        for (int s = 1; s < 64; s <<= 1) {
            pf += __shfl_xor(pf, s, 64);
            pe += __shfl_xor(pe, s, 64);
        }
        if (lane == 0) { sfc[k] = pf; sem[k] = pe; }
    }
    __syncthreads();

    if (wave == 0) {
        const float fcb = fc_b[0];
        const bool valid = lane < clen;
        float v = valid ? (sfc[lane] + fcb) : -3.0e38f;
        float m = v;
        #pragma unroll
        for (int s = 1; s < 64; s <<= 1) m = fmaxf(m, __shfl_xor(m, s, 64));
        const float e  = valid ? __expf(v - m) : 0.0f;
        const float ws = valid ? (e * sem[lane]) : 0.0f;
        float Z = e, S = ws;
        #pragma unroll
        for (int s = 1; s < 64; s <<= 1) {
            Z += __shfl_xor(Z, s, 64);
            S += __shfl_xor(S, s, 64);
        }
        if (lane == 0) {
            const float logit = S / Z + emo_b[0];
            out[bj] = 1.0f / (1.0f + __expf(-logit));
        }
    }
}

extern "C" void kernel_launch(void* const* d_in, const int* in_sizes, int n_in,
                              void* d_out, int out_size, void* d_ws, size_t ws_size,
                              hipStream_t stream) {
    const float* hs         = (const float*)d_in[0];
    const int*   clause_len = (const int*)d_in[1];
    const float* fc_w       = (const float*)d_in[2];
    const float* fc_b       = (const float*)d_in[3];
    const float* emo_w      = (const float*)d_in[4];
    const float* emo_b      = (const float*)d_in[5];
    float* out = (float*)d_out;

    clause_pool_kernel<<<NB * NJ, 256, 0, stream>>>(
        hs, clause_len, fc_w, fc_b, emo_w, emo_b, out);
}